// Round 1
// baseline (670.618 us; speedup 1.0000x reference)
//
#include <hip/hip_runtime.h>
#include <stdint.h>

#define D_MODEL 1024
#define NHEAD 16
#define HEAD_DIM 64
#define BATCH 4
#define SEQ 2048
#define ROWS (BATCH*SEQ)   // 8192

typedef __attribute__((ext_vector_type(8))) short short8;
typedef __attribute__((ext_vector_type(4))) float f32x4;
typedef unsigned short u16;

// fp32 -> bf16 round-to-nearest-even (no NaN inputs expected)
__device__ __forceinline__ u16 f2b(float f) {
  union { float f; uint32_t u; } in; in.f = f;
  uint32_t u = in.u;
  return (u16)((u + 0x7FFFu + ((u >> 16) & 1u)) >> 16);
}

// async global->LDS, 16B per lane; lds base must be wave-uniform (HW does base + lane*16)
__device__ __forceinline__ void async_lds16(const void* g, void* l) {
  __builtin_amdgcn_global_load_lds(
      (const __attribute__((address_space(1))) uint32_t*)g,
      (__attribute__((address_space(3))) uint32_t*)l,
      16, 0, 0);
}

// ---------------- fp32 -> bf16 bulk convert (one float4 per thread) ----------------
__global__ void __launch_bounds__(256) cvt_kernel(const float* __restrict__ in,
                                                  u16* __restrict__ out) {
  int i = blockIdx.x * 256 + threadIdx.x;   // grid sized exactly: 8192*256 threads
  float4 v = ((const float4*)in)[i];
  ushort4 o;
  o.x = f2b(v.x); o.y = f2b(v.y); o.z = f2b(v.z); o.w = f2b(v.w);
  ((ushort4*)out)[i] = o;
}

// ---------------- weight transpose + convert: wt[n][k] = bf16(w[k][n]) ----------------
__global__ void __launch_bounds__(256) wtrans_kernel(const float* __restrict__ w,
                                                     u16* __restrict__ wt) {
  __shared__ u16 tile[64 * 65];
  int t = threadIdx.x;
  int c = t & 63, rb = t >> 6;
  int k0 = blockIdx.x * 64, n0 = blockIdx.y * 64;
#pragma unroll
  for (int i = 0; i < 16; ++i) {
    int r = rb + i * 4;
    tile[c * 65 + r] = f2b(w[(size_t)(k0 + r) * D_MODEL + n0 + c]);
  }
  __syncthreads();
#pragma unroll
  for (int i = 0; i < 16; ++i) {
    int r = rb + i * 4;
    wt[(size_t)(n0 + r) * D_MODEL + k0 + c] = tile[r * 65 + c];
  }
}

// ---------------- GEMM core: C[M][N] = A[M][K] * Bt[N][K]^T + bias ----------------
// A, Bt bf16 row-major; 128x128 block tile, BK=32, 4 waves (2x2), 4x4 MFMA accs/wave.
template <bool F32OUT>
__device__ __forceinline__ void gemm_bt_core(const u16* __restrict__ A,
                                             const u16* __restrict__ Bt,
                                             const float* __restrict__ bias,
                                             void* __restrict__ Cout) {
  constexpr int K = 1024, N = 1024;
  __shared__ u16 As[128 * 32];
  __shared__ u16 Bs[128 * 32];
  int tid = threadIdx.x;
  int wave = tid >> 6, lane = tid & 63;
  int quad = lane >> 4, l16 = lane & 15;
  int wm = wave & 1, wn = wave >> 1;
  int m0 = blockIdx.y * 128, n0 = blockIdx.x * 128;

  f32x4 acc[4][4];
#pragma unroll
  for (int mi = 0; mi < 4; ++mi)
#pragma unroll
    for (int ni = 0; ni < 4; ++ni) acc[mi][ni] = f32x4{0.f, 0.f, 0.f, 0.f};

  int srow = lane >> 2;          // 0..15: tile row within 16-row chunk
  int scol = (lane & 3) * 16;    // byte offset within 64B tile row

  for (int k0 = 0; k0 < K; k0 += 32) {
#pragma unroll
    for (int i = 0; i < 2; ++i) {
      int c = wave * 2 + i;  // chunk 0..7, 16 rows each
      const char* ga = (const char*)(A + (size_t)(m0 + c * 16 + srow) * K + k0) + scol;
      async_lds16(ga, (char*)As + c * 1024);
      const char* gb = (const char*)(Bt + (size_t)(n0 + c * 16 + srow) * K + k0) + scol;
      async_lds16(gb, (char*)Bs + c * 1024);
    }
    __syncthreads();  // drains vmcnt: LDS tiles complete

    short8 af[4], bf[4];
#pragma unroll
    for (int mi = 0; mi < 4; ++mi)
      af[mi] = *(const short8*)(As + (wm * 64 + mi * 16 + l16) * 32 + quad * 8);
#pragma unroll
    for (int ni = 0; ni < 4; ++ni)
      bf[ni] = *(const short8*)(Bs + (wn * 64 + ni * 16 + l16) * 32 + quad * 8);
#pragma unroll
    for (int mi = 0; mi < 4; ++mi)
#pragma unroll
      for (int ni = 0; ni < 4; ++ni)
        acc[mi][ni] = __builtin_amdgcn_mfma_f32_16x16x32_bf16(af[mi], bf[ni], acc[mi][ni], 0, 0, 0);
    __syncthreads();  // protect LDS from next iteration's staging
  }

#pragma unroll
  for (int ni = 0; ni < 4; ++ni) {
    int col = n0 + wn * 64 + ni * 16 + l16;
    float bv = bias[col];
#pragma unroll
    for (int mi = 0; mi < 4; ++mi) {
      int row = m0 + wm * 64 + mi * 16 + quad * 4;
#pragma unroll
      for (int r = 0; r < 4; ++r) {
        float vv = acc[mi][ni][r] + bv;
        if (F32OUT)
          ((float*)Cout)[(size_t)(row + r) * N + col] = vv;
        else
          ((u16*)Cout)[(size_t)(row + r) * N + col] = f2b(vv);
      }
    }
  }
}

__global__ void __launch_bounds__(256) gemm_qkv_kernel(
    const u16* __restrict__ xb, const u16* __restrict__ yb,
    const u16* __restrict__ wqT, const u16* __restrict__ wkT, const u16* __restrict__ wvT,
    const float* __restrict__ bq, const float* __restrict__ bk, const float* __restrict__ bv,
    u16* __restrict__ q, u16* __restrict__ k, u16* __restrict__ v) {
  int z = blockIdx.z;
  const u16* A = (z == 0) ? xb : yb;
  const u16* Bt = (z == 0) ? wqT : (z == 1 ? wkT : wvT);
  const float* bias = (z == 0) ? bq : (z == 1 ? bk : bv);
  u16* C = (z == 0) ? q : (z == 1 ? k : v);
  gemm_bt_core<false>(A, Bt, bias, C);
}

__global__ void __launch_bounds__(256) gemm_o_kernel(const u16* __restrict__ ao,
                                                     const u16* __restrict__ woT,
                                                     const float* __restrict__ bo,
                                                     float* __restrict__ out) {
  gemm_bt_core<true>(ao, woT, bo, out);
}

// ---------------- flash attention ----------------
// grid: (SEQ/64, BATCH*NHEAD). Block = 256 thr = 4 waves; wave handles 16 q-rows.
// kv-tile = 32 keys. Layouts (verified m89/m91/m74):
//   A-frag: m = lane&15, k = quad*8+j ; B-frag: n = lane&15, k = quad*8+j
//   C/D:    col = lane&15, row = quad*4 + reg
__global__ void __launch_bounds__(256) attn_kernel(const u16* __restrict__ Q,
                                                   const u16* __restrict__ Kp,
                                                   const u16* __restrict__ V,
                                                   u16* __restrict__ Outp) {
  __shared__ u16 Ks[32 * 64];       // K-tile row-major [key][d]
  __shared__ u16 Vts[64 * 32];      // V-tile transposed [d][key]
  __shared__ u16 Ps[4][16 * 32];    // per-wave P tile [qrow][key]

  int tid = threadIdx.x, wave = tid >> 6, lane = tid & 63;
  int quad = lane >> 4, l16 = lane & 15;
  int bh = blockIdx.y;
  int b = bh >> 4, h = bh & 15;
  int q0 = blockIdx.x * 64 + wave * 16;
  size_t base = (size_t)b * SEQ * D_MODEL;
  size_t hoff = (size_t)h * HEAD_DIM;

  // Q A-frags (held in registers for whole kv loop): k-halves 0..31, 32..63
  short8 aq[2];
#pragma unroll
  for (int hf = 0; hf < 2; ++hf)
    aq[hf] = *(const short8*)(Q + base + (size_t)(q0 + l16) * D_MODEL + hoff + hf * 32 + quad * 8);

  float m_r[4], l_r[4];
  f32x4 Oacc[4];
#pragma unroll
  for (int r = 0; r < 4; ++r) { m_r[r] = -INFINITY; l_r[r] = 0.f; }
#pragma unroll
  for (int ni = 0; ni < 4; ++ni) Oacc[ni] = f32x4{0.f, 0.f, 0.f, 0.f};

  const float scale = 0.125f;  // 1/sqrt(64)

  for (int kv0 = 0; kv0 < SEQ; kv0 += 32) {
    __syncthreads();  // previous iteration's LDS reads done
    // stage K-tile: 4KB via 4 wave-chunks of 1KB
    {
      const char* g = (const char*)(Kp + base + (size_t)(kv0 + wave * 8 + (lane >> 3)) * D_MODEL +
                                    hoff + (size_t)(lane & 7) * 8);
      async_lds16(g, (char*)Ks + wave * 1024);
    }
    // stage V-tile transposed (coalesced 16B reads, scalar LDS writes)
    {
      int key = tid >> 3;
      int dbase = (tid & 7) * 8;
      short8 v8 = *(const short8*)(V + base + (size_t)(kv0 + key) * D_MODEL + hoff + dbase);
#pragma unroll
      for (int j = 0; j < 8; ++j) Vts[(dbase + j) * 32 + key] = (u16)v8[j];
    }
    __syncthreads();

    // S = Q * K^T for two 16-key subtiles
    f32x4 S[2];
#pragma unroll
    for (int sub = 0; sub < 2; ++sub) {
      const u16* kr = Ks + (sub * 16 + l16) * 64;
      short8 b0 = *(const short8*)(kr + quad * 8);
      short8 b1 = *(const short8*)(kr + 32 + quad * 8);
      f32x4 s = f32x4{0.f, 0.f, 0.f, 0.f};
      s = __builtin_amdgcn_mfma_f32_16x16x32_bf16(aq[0], b0, s, 0, 0, 0);
      s = __builtin_amdgcn_mfma_f32_16x16x32_bf16(aq[1], b1, s, 0, 0, 0);
      S[sub] = s;
    }

    // online softmax per q-row (row = quad*4+r, spread over 16 lanes = 16 keys)
    u16* Pw = Ps[wave];
#pragma unroll
    for (int r = 0; r < 4; ++r) {
      float s0 = S[0][r] * scale, s1 = S[1][r] * scale;
      float mx = fmaxf(s0, s1);
#pragma unroll
      for (int off = 8; off > 0; off >>= 1) mx = fmaxf(mx, __shfl_xor(mx, off));
      float mn = fmaxf(m_r[r], mx);
      float alpha = __expf(m_r[r] - mn);
      float p0 = __expf(s0 - mn), p1 = __expf(s1 - mn);
      float ps = p0 + p1;
#pragma unroll
      for (int off = 8; off > 0; off >>= 1) ps += __shfl_xor(ps, off);
      l_r[r] = l_r[r] * alpha + ps;
      m_r[r] = mn;
#pragma unroll
      for (int ni = 0; ni < 4; ++ni) Oacc[ni][r] *= alpha;
      // P: C-layout -> LDS (row-major 16x32), for A-layout readback
      Pw[(quad * 4 + r) * 32 + l16] = f2b(p0);
      Pw[(quad * 4 + r) * 32 + 16 + l16] = f2b(p1);
    }

    // P A-frag (same-wave LDS round-trip; compiler inserts lgkmcnt waits)
    short8 pa = *(const short8*)(Pw + l16 * 32 + quad * 8);
#pragma unroll
    for (int ni = 0; ni < 4; ++ni) {
      short8 bv = *(const short8*)(Vts + (ni * 16 + l16) * 32 + quad * 8);
      Oacc[ni] = __builtin_amdgcn_mfma_f32_16x16x32_bf16(pa, bv, Oacc[ni], 0, 0, 0);
    }
  }

  // epilogue: normalize and store bf16 attention output [B*S][D]
#pragma unroll
  for (int r = 0; r < 4; ++r) {
    float inv = 1.0f / l_r[r];
    size_t row = base + (size_t)(q0 + quad * 4 + r) * D_MODEL + hoff;
#pragma unroll
    for (int ni = 0; ni < 4; ++ni) Outp[row + ni * 16 + l16] = f2b(Oacc[ni][r] * inv);
  }
}

// ---------------- launch ----------------
extern "C" void kernel_launch(void* const* d_in, const int* in_sizes, int n_in,
                              void* d_out, int out_size, void* d_ws, size_t ws_size,
                              hipStream_t stream) {
  const float* x  = (const float*)d_in[0];
  const float* y  = (const float*)d_in[1];
  const float* wq = (const float*)d_in[2];
  const float* bq = (const float*)d_in[3];
  const float* wk = (const float*)d_in[4];
  const float* bk = (const float*)d_in[5];
  const float* wv = (const float*)d_in[6];
  const float* bv = (const float*)d_in[7];
  const float* wo = (const float*)d_in[8];
  const float* bo = (const float*)d_in[9];
  float* out = (float*)d_out;

  char* ws = (char*)d_ws;
  const size_t SZ_ACT = (size_t)ROWS * D_MODEL * 2;     // 16 MiB
  const size_t SZ_W   = (size_t)D_MODEL * D_MODEL * 2;  // 2 MiB
  u16* xb  = (u16*)(ws);
  u16* yb  = (u16*)(ws + SZ_ACT);
  u16* wqT = (u16*)(ws + 2 * SZ_ACT);
  u16* wkT = (u16*)(ws + 2 * SZ_ACT + SZ_W);
  u16* wvT = (u16*)(ws + 2 * SZ_ACT + 2 * SZ_W);
  u16* woT = (u16*)(ws + 2 * SZ_ACT + 3 * SZ_W);
  u16* qb  = (u16*)(ws + 2 * SZ_ACT + 4 * SZ_W);
  u16* kb  = (u16*)(ws + 3 * SZ_ACT + 4 * SZ_W);
  u16* vb  = (u16*)(ws + 4 * SZ_ACT + 4 * SZ_W);
  u16* ao  = (u16*)(ws + 5 * SZ_ACT + 4 * SZ_W);

  cvt_kernel<<<8192, 256, 0, stream>>>(x, xb);
  cvt_kernel<<<8192, 256, 0, stream>>>(y, yb);
  wtrans_kernel<<<dim3(16, 16), 256, 0, stream>>>(wq, wqT);
  wtrans_kernel<<<dim3(16, 16), 256, 0, stream>>>(wk, wkT);
  wtrans_kernel<<<dim3(16, 16), 256, 0, stream>>>(wv, wvT);
  wtrans_kernel<<<dim3(16, 16), 256, 0, stream>>>(wo, woT);
  gemm_qkv_kernel<<<dim3(8, 64, 3), 256, 0, stream>>>(xb, yb, wqT, wkT, wvT, bq, bk, bv, qb, kb, vb);
  attn_kernel<<<dim3(32, 64), 256, 0, stream>>>(qb, kb, vb, ao);
  gemm_o_kernel<<<dim3(8, 64), 256, 0, stream>>>(ao, woT, bo, out);
}

// Round 2
// 346.325 us; speedup vs baseline: 1.9364x; 1.9364x over previous
//
#include <hip/hip_runtime.h>
#include <stdint.h>

#define D_MODEL 1024
#define NHEAD 16
#define HEAD_DIM 64
#define BATCH 4
#define SEQ 2048
#define ROWS (BATCH*SEQ)   // 8192

typedef __attribute__((ext_vector_type(8))) short short8;
typedef __attribute__((ext_vector_type(4))) float f32x4;
typedef __attribute__((ext_vector_type(2))) unsigned int u32x2;
typedef unsigned short u16;
typedef unsigned int u32;

// log2(e)/8 folded into Q at projection time
#define QSCALE 0.18033688011112042f

// fp32 -> bf16 round-to-nearest-even
__device__ __forceinline__ u16 f2b(float f) {
  union { float f; uint32_t u; } in; in.f = f;
  uint32_t u = in.u;
  return (u16)((u + 0x7FFFu + ((u >> 16) & 1u)) >> 16);
}

// async global->LDS, 16B/lane; HW dest = wave-uniform base + lane*16
__device__ __forceinline__ void async_lds16(const void* g, void* l) {
  __builtin_amdgcn_global_load_lds(
      (const __attribute__((address_space(1))) uint32_t*)g,
      (__attribute__((address_space(3))) uint32_t*)l,
      16, 0, 0);
}

// pack two f32 into bf16x2 (round-half-up via +0x8000)
__device__ __forceinline__ u32 pack_bf16(float lo, float hi) {
  union { float f; uint32_t u; } a, b; a.f = lo; b.f = hi;
  return __builtin_amdgcn_perm(b.u + 0x8000u, a.u + 0x8000u, 0x07060302u);
}

// ---------------- fp32 -> bf16 bulk convert ----------------
__global__ void __launch_bounds__(256) cvt_kernel(const float* __restrict__ in,
                                                  u16* __restrict__ out) {
  int i = blockIdx.x * 256 + threadIdx.x;
  float4 v = ((const float4*)in)[i];
  ushort4 o;
  o.x = f2b(v.x); o.y = f2b(v.y); o.z = f2b(v.z); o.w = f2b(v.w);
  ((ushort4*)out)[i] = o;
}

// ---------------- weight transpose + convert: wt[n][k] = bf16(w[k][n]) ----------------
__global__ void __launch_bounds__(256) wtrans_kernel(const float* __restrict__ w,
                                                     u16* __restrict__ wt) {
  __shared__ u16 tile[64 * 65];
  int t = threadIdx.x;
  int c = t & 63, rb = t >> 6;
  int k0 = blockIdx.x * 64, n0 = blockIdx.y * 64;
#pragma unroll
  for (int i = 0; i < 16; ++i) {
    int r = rb + i * 4;
    tile[c * 65 + r] = f2b(w[(size_t)(k0 + r) * D_MODEL + n0 + c]);
  }
  __syncthreads();
#pragma unroll
  for (int i = 0; i < 16; ++i) {
    int r = rb + i * 4;
    wt[(size_t)(n0 + r) * D_MODEL + k0 + c] = tile[r * 65 + c];
  }
}

// ---------------- GEMM core: C[M][N] = A[M][K] * Bt[N][K]^T + bias ----------------
// MODE 0: bf16 row-major out, bias per col, scaled. MODE 1: f32 row-major out.
// MODE 2: V^T sigma-layout out (vt[(b*16+h)*64+d][sigma(s)]), bias per row.
template <int MODE>
__device__ __forceinline__ void gemm_bt_core(const u16* __restrict__ A,
                                             const u16* __restrict__ Bt,
                                             const float* __restrict__ bias,
                                             void* __restrict__ Cout, float scale) {
  constexpr int K = 1024, N = 1024;
  __shared__ u16 As[128 * 32];
  __shared__ u16 Bs[128 * 32];
  int tid = threadIdx.x;
  int wave = tid >> 6, lane = tid & 63;
  int quad = lane >> 4, l16 = lane & 15;
  int wm = wave & 1, wn = wave >> 1;
  int m0 = blockIdx.y * 128, n0 = blockIdx.x * 128;

  f32x4 acc[4][4];
#pragma unroll
  for (int mi = 0; mi < 4; ++mi)
#pragma unroll
    for (int ni = 0; ni < 4; ++ni) acc[mi][ni] = f32x4{0.f, 0.f, 0.f, 0.f};

  int srow = lane >> 2;
  int scol = (lane & 3) * 16;

  for (int k0 = 0; k0 < K; k0 += 32) {
#pragma unroll
    for (int i = 0; i < 2; ++i) {
      int c = wave * 2 + i;
      const char* ga = (const char*)(A + (size_t)(m0 + c * 16 + srow) * K + k0) + scol;
      async_lds16(ga, (char*)As + c * 1024);
      const char* gb = (const char*)(Bt + (size_t)(n0 + c * 16 + srow) * K + k0) + scol;
      async_lds16(gb, (char*)Bs + c * 1024);
    }
    __syncthreads();

    short8 af[4], bf[4];
#pragma unroll
    for (int mi = 0; mi < 4; ++mi)
      af[mi] = *(const short8*)(As + (wm * 64 + mi * 16 + l16) * 32 + quad * 8);
#pragma unroll
    for (int ni = 0; ni < 4; ++ni)
      bf[ni] = *(const short8*)(Bs + (wn * 64 + ni * 16 + l16) * 32 + quad * 8);
#pragma unroll
    for (int mi = 0; mi < 4; ++mi)
#pragma unroll
      for (int ni = 0; ni < 4; ++ni)
        acc[mi][ni] = __builtin_amdgcn_mfma_f32_16x16x32_bf16(af[mi], bf[ni], acc[mi][ni], 0, 0, 0);
    __syncthreads();
  }

  if (MODE == 2) {
    // row = d-col of V, col = s_glob. Store V^T with sigma key-interleave.
#pragma unroll
    for (int ni = 0; ni < 4; ++ni) {
      int col = n0 + wn * 64 + ni * 16 + l16;       // s_glob
      int bb = col >> 11, ss = col & 2047;
      size_t sbase = (size_t)(ss & ~63) + 4 * l16 + ni;  // sigma position
#pragma unroll
      for (int mi = 0; mi < 4; ++mi) {
        int row0 = m0 + wm * 64 + mi * 16 + quad * 4;
#pragma unroll
        for (int r = 0; r < 4; ++r) {
          int dcol = row0 + r;
          float vv = acc[mi][ni][r] + bias[dcol];
          int hh = dcol >> 6, dd = dcol & 63;
          size_t vtrow = ((size_t)bb * 16 + hh) * 64 + dd;
          ((u16*)Cout)[vtrow * 2048 + sbase] = f2b(vv);
        }
      }
    }
  } else {
#pragma unroll
    for (int ni = 0; ni < 4; ++ni) {
      int col = n0 + wn * 64 + ni * 16 + l16;
      float bv = bias[col];
#pragma unroll
      for (int mi = 0; mi < 4; ++mi) {
        int row = m0 + wm * 64 + mi * 16 + quad * 4;
#pragma unroll
        for (int r = 0; r < 4; ++r) {
          float vv = (acc[mi][ni][r] + bv) * scale;
          if (MODE == 1)
            ((float*)Cout)[(size_t)(row + r) * N + col] = vv;
          else
            ((u16*)Cout)[(size_t)(row + r) * N + col] = f2b(vv);
        }
      }
    }
  }
}

__global__ void __launch_bounds__(256) gemm_qk_kernel(
    const u16* __restrict__ xb, const u16* __restrict__ yb,
    const u16* __restrict__ wqT, const u16* __restrict__ wkT,
    const float* __restrict__ bq, const float* __restrict__ bk,
    u16* __restrict__ q, u16* __restrict__ k) {
  if (blockIdx.z == 0)
    gemm_bt_core<0>(xb, wqT, bq, q, QSCALE);
  else
    gemm_bt_core<0>(yb, wkT, bk, k, 1.0f);
}

__global__ void __launch_bounds__(256) gemm_v_kernel(const u16* __restrict__ wvT,
                                                     const u16* __restrict__ yb,
                                                     const float* __restrict__ bv,
                                                     u16* __restrict__ vt) {
  gemm_bt_core<2>(wvT, yb, bv, vt, 1.0f);
}

__global__ void __launch_bounds__(256) gemm_o_kernel(const u16* __restrict__ ao,
                                                     const u16* __restrict__ woT,
                                                     const float* __restrict__ bo,
                                                     float* __restrict__ out) {
  gemm_bt_core<1>(ao, woT, bo, out, 1.0f);
}

// ---------------- flash attention, no-max softmax ----------------
// grid (SEQ/128, B*H); block 256 = 4 waves; wave owns 32 q-rows.
// kv-tile = 64 keys. All LDS rows are 64 u16 (128B) with 8-u16 XOR swizzle
// chunk' = chunk ^ (row&7) to spread banks; sigma key-interleave
// sigma(t) = 4*(t&15) + (t>>4) baked into global Vt so P writes pack to b64.
__global__ void __launch_bounds__(256, 4) attn_kernel(const u16* __restrict__ Q,
                                                      const u16* __restrict__ Kp,
                                                      const u16* __restrict__ Vt,
                                                      u16* __restrict__ Outp) {
  __shared__ u16 Ks[64 * 64];        // [key][d-chunk^key&7]
  __shared__ u16 Vts[64 * 64];       // [d][sigma-chunk^d&7]
  __shared__ u16 Ps[4][32 * 64];     // per-wave P [row][sigma-chunk^row&7]

  int tid = threadIdx.x, wave = tid >> 6, lane = tid & 63;
  int quad = lane >> 4, l16 = lane & 15;
  int bh = blockIdx.y;
  int b = bh >> 4, h = bh & 15;
  int q0 = blockIdx.x * 128 + wave * 32;
  size_t gbase = (size_t)b * SEQ * D_MODEL;
  const u16* kbase = Kp + gbase + (size_t)h * HEAD_DIM;
  const u16* vbase = Vt + (size_t)bh * HEAD_DIM * SEQ;
  const u16* qrow = Q + gbase + (size_t)q0 * D_MODEL + (size_t)h * HEAD_DIM;

  // Q A-frags (scale pre-folded): aq[rowset][k-half]
  short8 aq[2][2];
#pragma unroll
  for (int rs = 0; rs < 2; ++rs)
#pragma unroll
    for (int dc = 0; dc < 2; ++dc)
      aq[rs][dc] = *(const short8*)(qrow + (size_t)(rs * 16 + l16) * D_MODEL + dc * 32 + quad * 8);

  f32x4 Oacc[2][4];
  float lpart[2][4];
#pragma unroll
  for (int rs = 0; rs < 2; ++rs)
#pragma unroll
    for (int ni = 0; ni < 4; ++ni) Oacc[rs][ni] = f32x4{0.f, 0.f, 0.f, 0.f};
#pragma unroll
  for (int rs = 0; rs < 2; ++rs)
#pragma unroll
    for (int r = 0; r < 4; ++r) lpart[rs][r] = 0.f;

  // staging offsets (u16 units), chunk c = i*256 + wave*64 + lane
  size_t koff[2], voff[2];
  int dstoff[2];
#pragma unroll
  for (int i = 0; i < 2; ++i) {
    int c = i * 256 + tid;
    int krow = c >> 3, kgp = c & 7;
    koff[i] = (size_t)krow * D_MODEL + (size_t)((kgp ^ (krow & 7)) * 8);
    voff[i] = (size_t)krow * SEQ + (size_t)((kgp ^ (krow & 7)) * 8);
    dstoff[i] = i * 4096 + wave * 1024;  // bytes
  }

  for (int kv0 = 0; kv0 < SEQ; kv0 += 64) {
    __syncthreads();  // all waves done reading previous tile
#pragma unroll
    for (int i = 0; i < 2; ++i) {
      async_lds16(kbase + (size_t)kv0 * D_MODEL + koff[i], (char*)Ks + dstoff[i]);
      async_lds16(vbase + (size_t)kv0 + voff[i], (char*)Vts + dstoff[i]);
    }
    __syncthreads();  // staging complete (barrier drains vmcnt)

    u16* Pw = Ps[wave];
#pragma unroll
    for (int rs = 0; rs < 2; ++rs) {
      f32x4 S[4];
#pragma unroll
      for (int sub = 0; sub < 4; ++sub) {
        int key = sub * 16 + l16;
        int x = l16 & 7;
        short8 b0 = *(const short8*)(Ks + key * 64 + ((quad ^ x) << 3));
        short8 b1 = *(const short8*)(Ks + key * 64 + (((4 + quad) ^ x) << 3));
        f32x4 s = f32x4{0.f, 0.f, 0.f, 0.f};
        s = __builtin_amdgcn_mfma_f32_16x16x32_bf16(aq[rs][0], b0, s, 0, 0, 0);
        s = __builtin_amdgcn_mfma_f32_16x16x32_bf16(aq[rs][1], b1, s, 0, 0, 0);
        S[sub] = s;
      }
#pragma unroll
      for (int r = 0; r < 4; ++r) {
        float p0 = __builtin_amdgcn_exp2f(S[0][r]);
        float p1 = __builtin_amdgcn_exp2f(S[1][r]);
        float p2 = __builtin_amdgcn_exp2f(S[2][r]);
        float p3 = __builtin_amdgcn_exp2f(S[3][r]);
        lpart[rs][r] += (p0 + p1) + (p2 + p3);
        u32 lo = pack_bf16(p0, p1);
        u32 hi = pack_bf16(p2, p3);
        int row = rs * 16 + quad * 4 + r;
        // b64 write at sigma base 4*l16, chunk-XOR'ed
        int off = row * 64 + (((l16 >> 1) ^ (row & 7)) << 3) + ((l16 & 1) << 2);
        *(u32x2*)(Pw + off) = u32x2{lo, hi};
      }
    }

    // PV: O += P * V  (sigma-space K-dim, consistent for P and Vt)
#pragma unroll
    for (int kc = 0; kc < 2; ++kc) {
      short8 pa[2];
#pragma unroll
      for (int rs = 0; rs < 2; ++rs) {
        int prow = rs * 16 + l16;
        pa[rs] = *(const short8*)(Pw + prow * 64 + ((((kc << 2) + quad) ^ (l16 & 7)) << 3));
      }
#pragma unroll
      for (int ni = 0; ni < 4; ++ni) {
        int d = ni * 16 + l16;
        short8 bv = *(const short8*)(Vts + d * 64 + ((((kc << 2) + quad) ^ (l16 & 7)) << 3));
        Oacc[0][ni] = __builtin_amdgcn_mfma_f32_16x16x32_bf16(pa[0], bv, Oacc[0][ni], 0, 0, 0);
        Oacc[1][ni] = __builtin_amdgcn_mfma_f32_16x16x32_bf16(pa[1], bv, Oacc[1][ni], 0, 0, 0);
      }
    }
  }

  // epilogue: reduce l across the 16 key-lanes, normalize, store bf16
#pragma unroll
  for (int rs = 0; rs < 2; ++rs)
#pragma unroll
    for (int r = 0; r < 4; ++r) {
      float l = lpart[rs][r];
      l += __shfl_xor(l, 1);
      l += __shfl_xor(l, 2);
      l += __shfl_xor(l, 4);
      l += __shfl_xor(l, 8);
      float inv = 1.0f / l;
      size_t orow = gbase + (size_t)(q0 + rs * 16 + quad * 4 + r) * D_MODEL + (size_t)h * HEAD_DIM;
#pragma unroll
      for (int ni = 0; ni < 4; ++ni)
        Outp[orow + ni * 16 + l16] = f2b(Oacc[rs][ni][r] * inv);
    }
}

// ---------------- launch ----------------
extern "C" void kernel_launch(void* const* d_in, const int* in_sizes, int n_in,
                              void* d_out, int out_size, void* d_ws, size_t ws_size,
                              hipStream_t stream) {
  const float* x  = (const float*)d_in[0];
  const float* y  = (const float*)d_in[1];
  const float* wq = (const float*)d_in[2];
  const float* bq = (const float*)d_in[3];
  const float* wk = (const float*)d_in[4];
  const float* bk = (const float*)d_in[5];
  const float* wv = (const float*)d_in[6];
  const float* bv = (const float*)d_in[7];
  const float* wo = (const float*)d_in[8];
  const float* bo = (const float*)d_in[9];
  float* out = (float*)d_out;

  char* ws = (char*)d_ws;
  const size_t SZ_ACT = (size_t)ROWS * D_MODEL * 2;     // 16 MiB
  const size_t SZ_W   = (size_t)D_MODEL * D_MODEL * 2;  // 2 MiB
  u16* xb  = (u16*)(ws);
  u16* yb  = (u16*)(ws + SZ_ACT);
  u16* wqT = (u16*)(ws + 2 * SZ_ACT);
  u16* wkT = (u16*)(ws + 2 * SZ_ACT + SZ_W);
  u16* wvT = (u16*)(ws + 2 * SZ_ACT + 2 * SZ_W);
  u16* woT = (u16*)(ws + 2 * SZ_ACT + 3 * SZ_W);
  u16* qb  = (u16*)(ws + 2 * SZ_ACT + 4 * SZ_W);
  u16* kb  = (u16*)(ws + 3 * SZ_ACT + 4 * SZ_W);
  u16* vt  = (u16*)(ws + 4 * SZ_ACT + 4 * SZ_W);
  u16* ao  = (u16*)(ws + 5 * SZ_ACT + 4 * SZ_W);

  cvt_kernel<<<8192, 256, 0, stream>>>(x, xb);
  cvt_kernel<<<8192, 256, 0, stream>>>(y, yb);
  wtrans_kernel<<<dim3(16, 16), 256, 0, stream>>>(wq, wqT);
  wtrans_kernel<<<dim3(16, 16), 256, 0, stream>>>(wk, wkT);
  wtrans_kernel<<<dim3(16, 16), 256, 0, stream>>>(wv, wvT);
  wtrans_kernel<<<dim3(16, 16), 256, 0, stream>>>(wo, woT);
  gemm_qk_kernel<<<dim3(8, 64, 2), 256, 0, stream>>>(xb, yb, wqT, wkT, bq, bk, qb, kb);
  gemm_v_kernel<<<dim3(64, 8), 256, 0, stream>>>(wvT, yb, bv, vt);
  attn_kernel<<<dim3(16, 64), 256, 0, stream>>>(qb, kb, vt, ao);
  gemm_o_kernel<<<dim3(8, 64), 256, 0, stream>>>(ao, woT, bo, out);
}